// Round 1
// baseline (3214.421 us; speedup 1.0000x reference)
//
#include <hip/hip_runtime.h>
#include <hip/hip_bf16.h>
#include <math.h>

#define BB 2048
#define NN 63
#define TOT_ROWS (BB * NN)   // 129024

// Persistent scratch (avoids depending on ws_size). Fully rewritten each launch.
__device__ float g_feat[TOT_ROWS * 256];   // [op_vec|c1|c2|bm] per node, 132 MB
__device__ float g_rep[TOT_ROWS * 128];    // tree representations, 66 MB

#define DOT4(A, X)                                            \
    A[0] += X.x * w0.x + X.y * w1.x + X.z * w2.x + X.w * w3.x; \
    A[1] += X.x * w0.y + X.y * w1.y + X.z * w2.y + X.w * w3.y; \
    A[2] += X.x * w0.z + X.y * w1.z + X.z * w2.z + X.w * w3.z; \
    A[3] += X.x * w0.w + X.y * w1.w + X.z * w2.w + X.w * w3.w;

#define DOT2(A, X)                                            \
    A[0] += X.x * w0.x + X.y * w1.x + X.z * w2.x + X.w * w3.x; \
    A[1] += X.x * w0.y + X.y * w1.y + X.z * w2.y + X.w * w3.y;

// ---------------------------------------------------------------------------
// Kernel A: per-node leaf features. 16 rows/block, 256 threads.
// Thread owns 1 row (rg = tid>>4) x 4 cols (j0 = (tid&15)*4).
// feat[row][0:64]=op_vec  [64:128]=c1  [128:192]=c2  [192:256]=bm
// ---------------------------------------------------------------------------
__global__ __launch_bounds__(256) void leaf_kernel(
    const float* __restrict__ op, const float* __restrict__ extra,
    const float* __restrict__ cond1, const float* __restrict__ cond2,
    const float* __restrict__ bitmap, const float* __restrict__ has_cond,
    const float* __restrict__ W_op, const float* __restrict__ b_op,
    const float* __restrict__ W_pred, const float* __restrict__ b_pred,
    const float* __restrict__ W_bm, const float* __restrict__ b_bm)
{
    __shared__ float s_xa[16][68];   // padded rows (bank spread)
    __shared__ float s_xb[16][68];
    __shared__ float s_W[64 * 64];   // weight stage (also 40x64 W_bm chunks)

    const int tid  = threadIdx.x;
    const int row0 = blockIdx.x * 16;
    const int rg   = tid >> 4;        // row 0..15
    const int j0   = (tid & 15) * 4;  // col group

    // ---- phase 1: op_vec = [op|extra] @ W_op + b_op ----
    for (int i = tid; i < 16 * 64; i += 256) {
        int r = i >> 6, c = i & 63;
        s_xa[r][c] = (c < 32) ? op[(row0 + r) * 32 + c]
                              : extra[(row0 + r) * 32 + (c - 32)];
    }
    for (int i = tid; i < 64 * 64; i += 256) s_W[i] = W_op[i];
    __syncthreads();
    {
        float a[4] = {b_op[j0], b_op[j0 + 1], b_op[j0 + 2], b_op[j0 + 3]};
        for (int k = 0; k < 64; k += 4) {
            float4 xv = *(const float4*)&s_xa[rg][k];
            float4 w0 = *(const float4*)&s_W[(k + 0) * 64 + j0];
            float4 w1 = *(const float4*)&s_W[(k + 1) * 64 + j0];
            float4 w2 = *(const float4*)&s_W[(k + 2) * 64 + j0];
            float4 w3 = *(const float4*)&s_W[(k + 3) * 64 + j0];
            DOT4(a, xv);
        }
        *(float4*)&g_feat[(row0 + rg) * 256 + 0 + j0] =
            make_float4(a[0], a[1], a[2], a[3]);
    }
    __syncthreads();

    // ---- phase 2+3: c1 = cond1 @ W_pred + b, c2 = cond2 @ W_pred + b ----
    for (int i = tid; i < 16 * 64; i += 256) {
        int r = i >> 6, c = i & 63;
        s_xa[r][c] = cond1[(row0 + r) * 64 + c];
        s_xb[r][c] = cond2[(row0 + r) * 64 + c];
    }
    for (int i = tid; i < 64 * 64; i += 256) s_W[i] = W_pred[i];
    __syncthreads();
    {
        float a[4] = {b_pred[j0], b_pred[j0 + 1], b_pred[j0 + 2], b_pred[j0 + 3]};
        float d[4] = {a[0], a[1], a[2], a[3]};
        for (int k = 0; k < 64; k += 4) {
            float4 xa = *(const float4*)&s_xa[rg][k];
            float4 xb = *(const float4*)&s_xb[rg][k];
            float4 w0 = *(const float4*)&s_W[(k + 0) * 64 + j0];
            float4 w1 = *(const float4*)&s_W[(k + 1) * 64 + j0];
            float4 w2 = *(const float4*)&s_W[(k + 2) * 64 + j0];
            float4 w3 = *(const float4*)&s_W[(k + 3) * 64 + j0];
            DOT4(a, xa);
            DOT4(d, xb);
        }
        *(float4*)&g_feat[(row0 + rg) * 256 + 64 + j0] =
            make_float4(a[0], a[1], a[2], a[3]);
        *(float4*)&g_feat[(row0 + rg) * 256 + 128 + j0] =
            make_float4(d[0], d[1], d[2], d[3]);
    }

    // ---- phase 4: bm = (bitmap @ W_bm + b_bm) * has_cond ----
    float* s_bm = &s_xa[0][0];  // 16*40 floats, row stride 40 (160B, 16B aligned)
    float a[4] = {b_bm[j0], b_bm[j0 + 1], b_bm[j0 + 2], b_bm[j0 + 3]};
    for (int kb = 0; kb < 25; ++kb) {
        __syncthreads();  // protect s_bm / s_W reuse
        for (int i = tid; i < 16 * 40; i += 256) {
            int r = i / 40, c = i - r * 40;
            s_bm[r * 40 + c] = bitmap[(row0 + r) * 1000 + kb * 40 + c];
        }
        for (int i = tid; i < 40 * 64; i += 256) s_W[i] = W_bm[kb * 40 * 64 + i];
        __syncthreads();
        for (int k = 0; k < 40; k += 4) {
            float4 xv = *(const float4*)&s_bm[rg * 40 + k];
            float4 w0 = *(const float4*)&s_W[(k + 0) * 64 + j0];
            float4 w1 = *(const float4*)&s_W[(k + 1) * 64 + j0];
            float4 w2 = *(const float4*)&s_W[(k + 2) * 64 + j0];
            float4 w3 = *(const float4*)&s_W[(k + 3) * 64 + j0];
            DOT4(a, xv);
        }
    }
    {
        float hc = has_cond[row0 + rg];
        *(float4*)&g_feat[(row0 + rg) * 256 + 192 + j0] =
            make_float4(a[0] * hc, a[1] * hc, a[2] * hc, a[3] * hc);
    }
}

// ---------------------------------------------------------------------------
// Kernel B: one tree level. 16 rows/block, 256 threads.
// x = [feat(256) | left(128) | right(128)] -> relu(x@W_r1+b) -> relu(h@W_r2+b)
// r1: thread owns 4 rows (rg=tid>>6, wave-uniform -> broadcast x reads)
//     x 4 cols (j0=(tid&63)*4).
// ---------------------------------------------------------------------------
__global__ __launch_bounds__(256) void level_kernel(
    const float* __restrict__ W_r1, const float* __restrict__ b_r1,
    const float* __restrict__ W_r2, const float* __restrict__ b_r2,
    int l)
{
    __shared__ float s_x[16 * 512];   // 32 KB (reused as h[16][256] after r1)
    __shared__ float s_w[32 * 256];   // 32 KB weight chunk

    const int tid  = threadIdx.x;
    const int row0 = blockIdx.x * 16;
    const int mask = (1 << l) - 1;

    // stage x
    for (int i = tid; i < 16 * 512; i += 256) {
        int r = i >> 9, c = i & 511;
        int m = row0 + r;
        int b = m >> l;
        int g = mask + (m & mask);   // global node index
        float v;
        if (c < 256) {
            v = g_feat[(b * 63 + g) * 256 + c];
        } else if (l == 5) {
            v = 0.0f;                 // leaves: zero children
        } else {
            int child = 2 * g + 1 + ((c >> 7) & 1);  // [256,384)->2g+1, [384,512)->2g+2
            v = g_rep[(b * 63 + child) * 128 + (c & 127)];
        }
        s_x[r * 512 + c] = v;
    }

    const int j0 = (tid & 63) * 4;
    const int rg = tid >> 6;    // wave-uniform row group
    float acc[4][4];
    for (int ci = 0; ci < 4; ++ci) {
        float bv = b_r1[j0 + ci];
        for (int ri = 0; ri < 4; ++ri) acc[ri][ci] = bv;
    }
    for (int kb = 0; kb < 16; ++kb) {
        __syncthreads();
        for (int i = tid; i < 32 * 256; i += 256) s_w[i] = W_r1[kb * 8192 + i];
        __syncthreads();
        for (int k = 0; k < 32; k += 4) {
            int kk = kb * 32 + k;
            float4 x0 = *(const float4*)&s_x[(rg * 4 + 0) * 512 + kk];
            float4 x1 = *(const float4*)&s_x[(rg * 4 + 1) * 512 + kk];
            float4 x2 = *(const float4*)&s_x[(rg * 4 + 2) * 512 + kk];
            float4 x3 = *(const float4*)&s_x[(rg * 4 + 3) * 512 + kk];
            float4 w0 = *(const float4*)&s_w[(k + 0) * 256 + j0];
            float4 w1 = *(const float4*)&s_w[(k + 1) * 256 + j0];
            float4 w2 = *(const float4*)&s_w[(k + 2) * 256 + j0];
            float4 w3 = *(const float4*)&s_w[(k + 3) * 256 + j0];
            DOT4(acc[0], x0);
            DOT4(acc[1], x1);
            DOT4(acc[2], x2);
            DOT4(acc[3], x3);
        }
    }
    __syncthreads();
    float* s_h = s_x;   // h[16][256] overlays dead x
    for (int ri = 0; ri < 4; ++ri)
        for (int ci = 0; ci < 4; ++ci)
            s_h[(rg * 4 + ri) * 256 + j0 + ci] = fmaxf(acc[ri][ci], 0.0f);

    // r2: thread owns 4 rows x 2 cols (j2=(tid&63)*2)
    const int j2 = (tid & 63) * 2;
    float acc2[4][2];
    for (int ci = 0; ci < 2; ++ci) {
        float bv = b_r2[j2 + ci];
        for (int ri = 0; ri < 4; ++ri) acc2[ri][ci] = bv;
    }
    for (int kb = 0; kb < 8; ++kb) {
        __syncthreads();   // first iter also publishes s_h
        for (int i = tid; i < 32 * 128; i += 256) s_w[i] = W_r2[kb * 4096 + i];
        __syncthreads();
        for (int k = 0; k < 32; k += 4) {
            int kk = kb * 32 + k;
            float2 w0 = *(const float2*)&s_w[(k + 0) * 128 + j2];
            float2 w1 = *(const float2*)&s_w[(k + 1) * 128 + j2];
            float2 w2 = *(const float2*)&s_w[(k + 2) * 128 + j2];
            float2 w3 = *(const float2*)&s_w[(k + 3) * 128 + j2];
            float4 h0 = *(const float4*)&s_h[(rg * 4 + 0) * 256 + kk];
            float4 h1 = *(const float4*)&s_h[(rg * 4 + 1) * 256 + kk];
            float4 h2 = *(const float4*)&s_h[(rg * 4 + 2) * 256 + kk];
            float4 h3 = *(const float4*)&s_h[(rg * 4 + 3) * 256 + kk];
            DOT2(acc2[0], h0);
            DOT2(acc2[1], h1);
            DOT2(acc2[2], h2);
            DOT2(acc2[3], h3);
        }
    }
    for (int ri = 0; ri < 4; ++ri) {
        int m = row0 + rg * 4 + ri;
        int b = m >> l;
        int g = mask + (m & mask);
        float2 v = make_float2(fmaxf(acc2[ri][0], 0.0f), fmaxf(acc2[ri][1], 0.0f));
        *(float2*)&g_rep[(b * 63 + g) * 128 + j2] = v;
    }
}

// ---------------------------------------------------------------------------
// Kernel C: heads. 32 rows/block. cost -> out[0:2048], card -> out[2048:4096]
// ---------------------------------------------------------------------------
__global__ __launch_bounds__(256) void head_kernel(
    const float* __restrict__ W_c1, const float* __restrict__ b_c1,
    const float* __restrict__ W_c2, const float* __restrict__ b_c2,
    const float* __restrict__ W_c3, const float* __restrict__ b_c3,
    const float* __restrict__ W_d1, const float* __restrict__ b_d1,
    const float* __restrict__ W_d2, const float* __restrict__ b_d2,
    const float* __restrict__ W_d3, const float* __restrict__ b_d3,
    float* __restrict__ out)
{
    __shared__ float s_r[32 * 128];
    __shared__ float s_h1[32 * 64];
    __shared__ float s_h2[32 * 64];

    const int tid  = threadIdx.x;
    const int row0 = blockIdx.x * 32;
    for (int i = tid; i < 32 * 128; i += 256) {
        int r = i >> 7, c = i & 127;
        s_r[i] = g_rep[((row0 + r) * 63 + 0) * 128 + c];
    }
    __syncthreads();

    const int j  = tid & 63;
    const int rg = tid >> 6;   // 4 groups x 8 rows
    for (int head = 0; head < 2; ++head) {
        const float* W1 = head ? W_d1 : W_c1;
        const float* B1 = head ? b_d1 : b_c1;
        const float* W2 = head ? W_d2 : W_c2;
        const float* B2 = head ? b_d2 : b_c2;
        const float* W3 = head ? W_d3 : W_c3;
        const float* B3 = head ? b_d3 : b_c3;

        float acc[8];
        for (int t = 0; t < 8; ++t) acc[t] = B1[j];
        for (int k = 0; k < 128; ++k) {
            float w = W1[k * 64 + j];
            for (int t = 0; t < 8; ++t) acc[t] += s_r[(rg * 8 + t) * 128 + k] * w;
        }
        for (int t = 0; t < 8; ++t)
            s_h1[(rg * 8 + t) * 64 + j] = fmaxf(acc[t], 0.0f);
        __syncthreads();

        float acc2[8];
        for (int t = 0; t < 8; ++t) acc2[t] = B2[j];
        for (int k = 0; k < 64; ++k) {
            float w = W2[k * 64 + j];
            for (int t = 0; t < 8; ++t) acc2[t] += s_h1[(rg * 8 + t) * 64 + k] * w;
        }
        for (int t = 0; t < 8; ++t)
            s_h2[(rg * 8 + t) * 64 + j] = fmaxf(acc2[t], 0.0f);
        __syncthreads();

        if (tid < 32) {
            float s = B3[0];
            for (int k = 0; k < 64; ++k) s += s_h2[tid * 64 + k] * W3[k];
            out[head * BB + row0 + tid] = 1.0f / (1.0f + expf(-s));
        }
        __syncthreads();
    }
}

extern "C" void kernel_launch(void* const* d_in, const int* in_sizes, int n_in,
                              void* d_out, int out_size, void* d_ws, size_t ws_size,
                              hipStream_t stream)
{
    (void)in_sizes; (void)n_in; (void)out_size; (void)d_ws; (void)ws_size;
    const float* op       = (const float*)d_in[0];
    const float* extra    = (const float*)d_in[1];
    const float* cond1    = (const float*)d_in[2];
    const float* cond2    = (const float*)d_in[3];
    const float* bitmap   = (const float*)d_in[4];
    const float* has_cond = (const float*)d_in[5];
    const float* W_op  = (const float*)d_in[6];  const float* b_op  = (const float*)d_in[7];
    const float* W_pred= (const float*)d_in[8];  const float* b_pred= (const float*)d_in[9];
    const float* W_bm  = (const float*)d_in[10]; const float* b_bm  = (const float*)d_in[11];
    const float* W_r1  = (const float*)d_in[12]; const float* b_r1  = (const float*)d_in[13];
    const float* W_r2  = (const float*)d_in[14]; const float* b_r2  = (const float*)d_in[15];
    const float* W_c1  = (const float*)d_in[16]; const float* b_c1  = (const float*)d_in[17];
    const float* W_c2  = (const float*)d_in[18]; const float* b_c2  = (const float*)d_in[19];
    const float* W_c3  = (const float*)d_in[20]; const float* b_c3  = (const float*)d_in[21];
    const float* W_d1  = (const float*)d_in[22]; const float* b_d1  = (const float*)d_in[23];
    const float* W_d2  = (const float*)d_in[24]; const float* b_d2  = (const float*)d_in[25];
    const float* W_d3  = (const float*)d_in[26]; const float* b_d3  = (const float*)d_in[27];
    float* out = (float*)d_out;

    leaf_kernel<<<TOT_ROWS / 16, 256, 0, stream>>>(
        op, extra, cond1, cond2, bitmap, has_cond,
        W_op, b_op, W_pred, b_pred, W_bm, b_bm);

    for (int l = 5; l >= 0; --l) {
        int blocks = (BB << l) / 16;
        level_kernel<<<blocks, 256, 0, stream>>>(W_r1, b_r1, W_r2, b_r2, l);
    }

    head_kernel<<<BB / 32, 256, 0, stream>>>(
        W_c1, b_c1, W_c2, b_c2, W_c3, b_c3,
        W_d1, b_d1, W_d2, b_d2, W_d3, b_d3, out);
}